// Round 9
// baseline (222.909 us; speedup 1.0000x reference)
//
#include <hip/hip_runtime.h>
#include <cmath>

typedef _Float16 half8 __attribute__((ext_vector_type(8)));
typedef float f32x4 __attribute__((ext_vector_type(4)));

#define GLD_LDS16(gptr, lptr)                                                  \
  __builtin_amdgcn_global_load_lds(                                            \
      (const __attribute__((address_space(1))) void*)(gptr),                   \
      (__attribute__((address_space(3))) void*)(lptr), 16, 0, 0)

#define MEMFENCE asm volatile("" ::: "memory")

// ---------------- x: f32 -> f16 (vectorized, grid-stride) -------------------
__global__ void cvt_x(const float* __restrict__ in, _Float16* __restrict__ out,
                      long n) {
  long stride = (long)gridDim.x * blockDim.x * 8;
  for (long i = ((long)blockIdx.x * blockDim.x + threadIdx.x) * 8; i < n;
       i += stride) {
    const float4* p = (const float4*)(in + i);
    float4 a = p[0];
    float4 c = p[1];
    half8 h = {(_Float16)a.x, (_Float16)a.y, (_Float16)a.z, (_Float16)a.w,
               (_Float16)c.x, (_Float16)c.y, (_Float16)c.z, (_Float16)c.w};
    *(half8*)(out + i) = h;
  }
}

// ---------------- W: f32 -> f16 MFMA-fragment-packed ------------------------
// Fragment f = n16*(K/32) + k32 : 512 f16 (1 KB). Lane l of a reading wave
// gets elems  B[n16*16 + (l&15)][k32*32 + (l>>4)*8 + j]  at  Bp[f*512+l*8+j]
// -> a wave reads one fragment as a single coalesced global_load_dwordx4.
// One wave packs 4 consecutive k32 (one "group", 4 KB out, 16 rows x 256 B in).
// Tensors: We [2048x1024] (1024 groups) | Wl [3*2048 x 2048] (6144) |
//          Wh [1024x2048] (1024).  4 waves/block -> 2048 blocks.
__global__ void cvt_pack(const float* __restrict__ We,
                         const float* __restrict__ Wl,
                         const float* __restrict__ Wh,
                         _Float16* __restrict__ Pe, _Float16* __restrict__ Pl,
                         _Float16* __restrict__ Ph) {
  int g = blockIdx.x * 4 + (threadIdx.x >> 6);
  const int lane = threadIdx.x & 63;
  const float* W;
  _Float16* P;
  int K;
  if (g < 1024) {
    W = We; P = Pe; K = 1024;
  } else if (g < 1024 + 6144) {
    W = Wl; P = Pl; K = 2048; g -= 1024;
  } else {
    W = Wh; P = Ph; K = 2048; g -= 1024 + 6144;
  }
  const int gk = K >> 7;  // groups per row-block = K/128
  const int n16 = g / gk;
  const int k32b = (g - n16 * gk) * 4;
  const int row = n16 * 16 + (lane & 15);
  const int kb = (lane >> 4) * 8;
  const float* src = W + (size_t)row * K + kb;
  _Float16* dst = P + (((size_t)n16 * (K >> 5) + k32b) << 9) + (lane << 3);
#pragma unroll
  for (int f = 0; f < 4; f++) {
    const float4* p = (const float4*)(src + (k32b + f) * 32);
    float4 a = p[0];
    float4 c = p[1];
    half8 h = {(_Float16)a.x, (_Float16)a.y, (_Float16)a.z, (_Float16)a.w,
               (_Float16)c.x, (_Float16)c.y, (_Float16)c.z, (_Float16)c.w};
    *(half8*)(dst + (f << 9)) = h;
  }
}

// ---------------- GEMM: C[m,n] = sum_k A[m,k]*B[n,k] ------------------------
// A: K-major f16 (LDS-staged). B: fragment-packed f16 (registers, from L2).
// EPI: 0 = acc+bias -> f16 ; 1 = 0.5*tanh(acc+bias) -> f16 ; 2 = acc+bias -> f32
// NW:  B-fragments per wave. BN = NW*32 (4 -> BN=128, 2 -> BN=64).
// BM=256, BK=64, 512 threads = 8 waves (4M x 2N), wave tile 64 x (BN/2).
// LDS carries ONLY A (64 KB double-buffer): per K-tile 32 KB write + 64 KB
// read ~ 1130 cy < MFMA floor 1242 cy -> matrix pipe becomes top pipe.
// B-fragments: 2*NW coalesced dwordx4 loads/wave/K-tile, prefetched one tile
// ahead into registers; unrolled-x2 loop gives static reg double-buffering.
// Boundary (1 barrier/K-tile): vmcnt(2*NW) waits only A(t+1)'s gld_lds
// (B(t+1) stays in flight; compiler emits the exact b-reg vmcnt itself),
// lgkmcnt(0) = my A-reads drained (WAR for buffer swap), s_barrier.
// T2 XOR swizzle on A (pre-swizzled source + ds_read). setprio around MFMA.
// Grid: 256 blocks = 16x16 tiles; 2-D XCD rects (4 rows x 8 cols of tiles).
template <int EPI, int NW>
__global__ __launch_bounds__(512, 2) void gemmbr(
    const _Float16* __restrict__ A, const _Float16* __restrict__ Bp,
    const float* __restrict__ bias, void* __restrict__ Cout, int N, int K) {
  __shared__ _Float16 As[2][256 * 64];

  const int tid = threadIdx.x;
  const int lane = tid & 63;
  const int wave = tid >> 6;
  constexpr int BN = NW * 32;

  // 2-D XCD rects on the 16x16 tile grid (256 blocks): each XCD owns 4x8.
  const int bid = blockIdx.x;
  const int xcd = bid & 7;
  const int idx = bid >> 3;
  const int brow = ((xcd >> 1) * 4 + (idx & 3)) * 256;
  const int bcol = ((xcd & 1) * 8 + (idx >> 2)) * BN;

  const int wr = (wave >> 1) * 64;       // 4 M-waves
  const int wc = (wave & 1) * (BN / 2);  // 2 N-waves

  // A staging: 512 thr x 16B = 64 rows x 64 cols per issue; 4 issues/tile.
  const int sr = tid >> 3;
  const int sc = ((tid & 7) ^ (sr & 7)) * 8;  // T2 pre-swizzled source col
  const _Float16* Ag = A + (size_t)(brow + sr) * K + sc;
  const int ldst = tid * 8;

  // MFMA fragment geometry (16x16x32): row=lane&15, k-half=(lane>>4)*8
  const int frow = lane & 15;
  const int hi = lane >> 4;
  const int xr = lane & 7;

  int aoff[4];
#pragma unroll
  for (int m = 0; m < 4; m++) aoff[m] = (wr + m * 16 + frow) * 64;
  const int ch0 = (hi ^ xr) * 8;
  const int ch1 = ((4 + hi) ^ xr) * 8;

  // B fragment base for this wave (lane offset folded in)
  const int k32n = K >> 5;  // frags per col-block
  const _Float16* Bw =
      Bp + (((size_t)((bcol + wc) >> 4) * k32n) << 9) + (lane << 3);

  f32x4 acc[4][NW];
#pragma unroll
  for (int m = 0; m < 4; m++)
#pragma unroll
    for (int n = 0; n < NW; n++) acc[m][n] = f32x4{0.f, 0.f, 0.f, 0.f};

  auto stageA = [&](_Float16* sa, int t) {
    const _Float16* ag = Ag + t * 64;
#pragma unroll
    for (int i = 0; i < 4; i++)
      GLD_LDS16(ag + (size_t)i * 64 * K, sa + i * 4096 + ldst);
  };
  auto loadB = [&](half8 (&br)[NW][2], int t) {
#pragma unroll
    for (int n = 0; n < NW; n++)
#pragma unroll
      for (int kk = 0; kk < 2; kk++)
        br[n][kk] = *(const half8*)(Bw +
                                    (((size_t)n * k32n + t * 2 + kk) << 9));
  };

  const int nt = K >> 6;  // even (16 or 32)
  half8 bA[NW][2], bB[NW][2];

  // prologue: tile 0 fully resident, published
  stageA(As[0], 0);
  loadB(bA, 0);
  asm volatile("s_waitcnt vmcnt(0)" ::: "memory");
  __builtin_amdgcn_s_barrier();
  MEMFENCE;

  // one half-K-tile step: read tile from rdbuf, compute with bu;
  // stage A(ts)->stbuf and load B(ts)->bl; boundary wait + barrier.
  auto half_step = [&](const _Float16* rdbuf, _Float16* stbuf,
                       half8 (&bu)[NW][2], half8 (&bl)[NW][2], int ts) {
    const bool pf = ts < nt;
    if (pf) {
      stageA(stbuf, ts);
      loadB(bl, ts);
    }
    half8 a0[4], a1[4];
#pragma unroll
    for (int m = 0; m < 4; m++) a0[m] = *(const half8*)(rdbuf + aoff[m] + ch0);
#pragma unroll
    for (int m = 0; m < 4; m++) a1[m] = *(const half8*)(rdbuf + aoff[m] + ch1);
    __builtin_amdgcn_s_setprio(1);
#pragma unroll
    for (int m = 0; m < 4; m++)
#pragma unroll
      for (int n = 0; n < NW; n++)
        acc[m][n] =
            __builtin_amdgcn_mfma_f32_16x16x32_f16(a0[m], bu[n][0], acc[m][n], 0, 0, 0);
#pragma unroll
    for (int m = 0; m < 4; m++)
#pragma unroll
      for (int n = 0; n < NW; n++)
        acc[m][n] =
            __builtin_amdgcn_mfma_f32_16x16x32_f16(a1[m], bu[n][1], acc[m][n], 0, 0, 0);
    __builtin_amdgcn_s_setprio(0);
    // boundary: A(ts) landed (only B(ts)'s 2*NW loads may stay in flight)
    asm volatile("s_waitcnt vmcnt(%0)" ::"i"(2 * NW) : "memory");
    asm volatile("s_waitcnt lgkmcnt(0)" ::: "memory");
    __builtin_amdgcn_s_barrier();
    MEMFENCE;
  };

  for (int t = 0; t < nt; t += 2) {
    half_step(As[0], As[1], bA, bB, t + 1);  // tile t
    half_step(As[1], As[0], bB, bA, t + 2);  // tile t+1
  }

  // epilogue: C/D layout col = lane&15, row = (lane>>4)*4 + reg
  const int r0 = hi * 4;
  const int c0 = frow;
#pragma unroll
  for (int n = 0; n < NW; n++) {
    const int col = bcol + wc + n * 16 + c0;
    const float bv = bias[col];
#pragma unroll
    for (int m = 0; m < 4; m++) {
#pragma unroll
      for (int r = 0; r < 4; r++) {
        const int row = brow + wr + m * 16 + r0 + r;
        float v = acc[m][n][r] + bv;
        if (EPI == 1) v = 0.5f * tanhf(v);
        if (EPI == 2)
          ((float*)Cout)[(size_t)row * N + col] = v;
        else
          ((_Float16*)Cout)[(size_t)row * N + col] = (_Float16)v;
      }
    }
  }
}

// ---------------------------------------------------------------------------
extern "C" void kernel_launch(void* const* d_in, const int* in_sizes, int n_in,
                              void* d_out, int out_size, void* d_ws,
                              size_t ws_size, hipStream_t stream) {
  (void)in_sizes;
  (void)n_in;
  (void)out_size;
  (void)ws_size;

  const float* x = (const float*)d_in[0];        // [4096,1024]
  const float* W_embed = (const float*)d_in[1];  // [2048,1024]
  const float* b_embed = (const float*)d_in[2];  // [2048]
  const float* W_layers = (const float*)d_in[3]; // [3,2048,2048]
  const float* b_layers = (const float*)d_in[4]; // [3,2048]
  const float* W_head = (const float*)d_in[5];   // [1024,2048]
  const float* b_head = (const float*)d_in[6];   // [1024]

  const int B = 4096, I = 1024, H = 2048, O = 1024;

  char* w = (char*)d_ws;
  auto carve = [&](size_t bytes) {
    char* p = w;
    w += (bytes + 255) & ~(size_t)255;
    return p;
  };
  _Float16* xh = (_Float16*)carve((size_t)B * I * 2);
  _Float16* Pe = (_Float16*)carve((size_t)H * I * 2);   // packed W_embed
  _Float16* Pl = (_Float16*)carve((size_t)3 * H * H * 2);  // packed W_layers
  _Float16* Ph = (_Float16*)carve((size_t)O * H * 2);   // packed W_head
  _Float16* bufE = (_Float16*)carve((size_t)B * H * 2);
  _Float16* bufA = (_Float16*)carve((size_t)B * H * 2);

  cvt_x<<<1024, 256, 0, stream>>>(x, xh, (long)B * I);
  cvt_pack<<<2048, 256, 0, stream>>>(W_embed, W_layers, W_head, Pe, Pl, Ph);

  dim3 blk(512);
  // all grids: 16x16 tiles = 256 blocks
  // x_emb = x @ W_embed^T + b_embed            [B,H], f16
  gemmbr<0, 4><<<256, blk, 0, stream>>>(xh, Pe, b_embed, bufE, H, I);
  // h0 = 0.5*tanh(x_emb @ W0^T + b0)           [B,H], f16
  gemmbr<1, 4><<<256, blk, 0, stream>>>(bufE, Pl, b_layers, bufA, H, H);
  // h1 = 0.5*tanh(h0 @ W1^T + b1)              [B,H], f16
  gemmbr<1, 4><<<256, blk, 0, stream>>>(bufA, Pl + (size_t)H * H,
                                        b_layers + H, bufE, H, H);
  // h2 = 0.5*tanh(h1 @ W2^T + b2)              [B,H], f16
  gemmbr<1, 4><<<256, blk, 0, stream>>>(bufE, Pl + (size_t)2 * H * H,
                                        b_layers + 2 * H, bufA, H, H);
  // out = h2 @ W_head^T + b_head               [B,O], f32  (BN=64)
  gemmbr<2, 2><<<256, blk, 0, stream>>>(bufA, Ph, b_head, d_out, O, H);
}

// Round 10
// 205.590 us; speedup vs baseline: 1.0842x; 1.0842x over previous
//
#include <hip/hip_runtime.h>
#include <cmath>

typedef _Float16 half8 __attribute__((ext_vector_type(8)));
typedef float f32x4 __attribute__((ext_vector_type(4)));

#define GLD_LDS16(gptr, lptr)                                                  \
  __builtin_amdgcn_global_load_lds(                                            \
      (const __attribute__((address_space(1))) void*)(gptr),                   \
      (__attribute__((address_space(3))) void*)(lptr), 16, 0, 0)

#define MEMFENCE asm volatile("" ::: "memory")

// ---------------- merged f32 -> f16 conversion (one dispatch) ---------------
__global__ void cvt_all(const float* __restrict__ s0, const float* __restrict__ s1,
                        const float* __restrict__ s2, const float* __restrict__ s3,
                        _Float16* __restrict__ d0, _Float16* __restrict__ d1,
                        _Float16* __restrict__ d2, _Float16* __restrict__ d3,
                        long nb0, long nb1, long nb2) {
  long b = blockIdx.x;
  const float* s;
  _Float16* d;
  if (b < nb0) {
    s = s0; d = d0;
  } else if (b < nb0 + nb1) {
    s = s1; d = d1; b -= nb0;
  } else if (b < nb0 + nb1 + nb2) {
    s = s2; d = d2; b -= nb0 + nb1;
  } else {
    s = s3; d = d3; b -= nb0 + nb1 + nb2;
  }
  long i = b * 2048 + (long)threadIdx.x * 8;
  const float4* p = (const float4*)(s + i);
  float4 a = p[0];
  float4 c = p[1];
  half8 h = {(_Float16)a.x, (_Float16)a.y, (_Float16)a.z, (_Float16)a.w,
             (_Float16)c.x, (_Float16)c.y, (_Float16)c.z, (_Float16)c.w};
  *(half8*)(d + i) = h;
}

// ---------------- GEMM: C[m,n] = sum_k A[m,k]*B[n,k]  (both K-major) --------
// EPI: 0 = acc+bias -> f16 ; 1 = 0.5*tanh(acc+bias) -> f16 ; 2 = acc+bias -> f32
// NW:  B-fragments per wave. BN = NW*32 (4 -> BN=128, 2 -> BN=64).
// BM=256, BK=64, 512 threads = 8 waves (4M x 2N), wave tile 64 x (BN/2).
// r7 skeleton (triple-buffer, distance-2 prefetch, counted vmcnt once per
// K-tile) + m201 fine-phase anatomy: each K-tile = 4 phases (kk x nh), each
//   { ds_read subtile (A4+B2 or B2) || stage-part of tile t+2 (2/2/1/1)
//     -> s_barrier -> setprio(1) 8 MFMA setprio(0) -> s_barrier }
// vmcnt(LPT) only at phase (1,1): tile t+1 landed, t+2's LPT loads in
// flight — never drains mid-loop (T4). Barriers pace waves so each wave's
// LDS reads run under co-resident waves' MFMA windows (T3 -> enables T5).
// RAW: tile t validated at iter t-1's vmcnt+barrier. WAR: reads of a buffer
// retire (compiler lgkmcnt before MFMA) before their wave passes the
// post-MFMA barrier, which precedes any re-staging of that buffer.
// T2 XOR swizzle (chunk^row&7) via pre-swizzled global source + ds_read.
// Grid: 256 blocks = 16x16 tiles; 2-D XCD rects (4 rows x 8 cols of tiles).
template <int EPI, int NW>
__global__ __launch_bounds__(512, 2) void gemm4p(
    const _Float16* __restrict__ A, const _Float16* __restrict__ Bm,
    const float* __restrict__ bias, void* __restrict__ Cout, int N, int K) {
  constexpr int BN = NW * 32;
  constexpr int BLOADS = BN / 64;  // B staging issues per tile (2 or 1)
  constexpr int LPT = 4 + BLOADS;  // gld_lds issues per tile
  constexpr int NB = NW / 2;       // B-frags (and MFMAs/m) per phase
  __shared__ _Float16 As[3][256 * 64];
  __shared__ _Float16 Bs[3][BN * 64];

  const int tid = threadIdx.x;
  const int lane = tid & 63;
  const int wave = tid >> 6;

  // 2-D XCD rects on the 16x16 tile grid (256 blocks): each XCD owns 4x8.
  const int bid = blockIdx.x;
  const int xcd = bid & 7;
  const int idx = bid >> 3;  // 0..31
  const int brow = ((xcd >> 1) * 4 + (idx & 3)) * 256;
  const int bcol = ((xcd & 1) * 8 + (idx >> 2)) * BN;

  const int wr = (wave >> 1) * 64;        // 4 M-waves, 64 rows each
  const int wc = (wave & 1) * (BN / 2);   // 2 N-waves

  // staging: 512 thr x 16B covers 64 rows x 64 f16 cols per issue.
  const int sr = tid >> 3;
  const int sc = ((tid & 7) ^ (sr & 7)) * 8;  // T2: pre-swizzled source col
  const _Float16* Ag = A + (size_t)(brow + sr) * K + sc;
  const _Float16* Bg = Bm + (size_t)(bcol + sr) * K + sc;
  const int ldst = tid * 8;  // linear LDS dest (required by global_load_lds)

  // MFMA fragment geometry (16x16x32): row=lane&15, k-half=(lane>>4)*8
  const int frow = lane & 15;
  const int hi = lane >> 4;
  const int xr = lane & 7;  // read-side XOR (matches source swizzle)

  int aoff[4], boff[NW];
#pragma unroll
  for (int m = 0; m < 4; m++) aoff[m] = (wr + m * 16 + frow) * 64;
#pragma unroll
  for (int n = 0; n < NW; n++) boff[n] = (wc + n * 16 + frow) * 64;
  const int ch0 = (hi ^ xr) * 8;
  const int ch1 = ((4 + hi) ^ xr) * 8;

  f32x4 acc[4][NW];
#pragma unroll
  for (int m = 0; m < 4; m++)
#pragma unroll
    for (int n = 0; n < NW; n++) acc[m][n] = f32x4{0.f, 0.f, 0.f, 0.f};

  _Float16* sa0 = As[0]; _Float16* sa1 = As[1]; _Float16* sa2 = As[2];
  _Float16* sb0 = Bs[0]; _Float16* sb1 = Bs[1]; _Float16* sb2 = Bs[2];

  // staging parts (target = sa2/sb2, the buffer freed last iteration)
  auto stA01 = [&](int t) {
    GLD_LDS16(Ag + t * 64, sa2 + ldst);
    GLD_LDS16(Ag + t * 64 + (size_t)64 * K, sa2 + 4096 + ldst);
  };
  auto stA23 = [&](int t) {
    GLD_LDS16(Ag + t * 64 + (size_t)128 * K, sa2 + 8192 + ldst);
    GLD_LDS16(Ag + t * 64 + (size_t)192 * K, sa2 + 12288 + ldst);
  };
  auto stB0 = [&](int t) { GLD_LDS16(Bg + t * 64, sb2 + ldst); };
  auto stB1 = [&](int t) {
    if constexpr (BLOADS == 2)
      GLD_LDS16(Bg + t * 64 + (size_t)64 * K, sb2 + 4096 + ldst);
  };
  auto stageAll = [&](_Float16* sa, _Float16* sb, int t) {
#pragma unroll
    for (int i = 0; i < 4; i++)
      GLD_LDS16(Ag + t * 64 + (size_t)i * 64 * K, sa + i * 4096 + ldst);
#pragma unroll
    for (int i = 0; i < BLOADS; i++)
      GLD_LDS16(Bg + t * 64 + (size_t)i * 64 * K, sb + i * 4096 + ldst);
  };

  const int nt = K >> 6;  // 16 or 32 here

  // prologue: stage tiles 0,1; wait tile 0 (tile 1 stays in flight); publish
  stageAll(sa0, sb0, 0);
  stageAll(sa1, sb1, 1);
  asm volatile("s_waitcnt vmcnt(%0)" ::"i"(LPT) : "memory");
  __builtin_amdgcn_s_barrier();
  MEMFENCE;

  half8 a[4], b[NB];

  // one phase: optionally read A-frags (kk-half), read NB B-frags, issue a
  // staging part, barrier, 4*NB MFMA, barrier.
  auto phase = [&](int kk, int nh, int sp, int ts, bool dovm) {
    const int ch = kk ? ch1 : ch0;
    if (nh == 0) {
#pragma unroll
      for (int m = 0; m < 4; m++) a[m] = *(const half8*)(sa0 + aoff[m] + ch);
    }
#pragma unroll
    for (int j = 0; j < NB; j++)
      b[j] = *(const half8*)(sb0 + boff[nh * NB + j] + ch);
    if (ts < nt) {
      if (sp == 0) stA01(ts);
      else if (sp == 1) stA23(ts);
      else if (sp == 2) stB0(ts);
      else stB1(ts);
    }
    MEMFENCE;
    if (dovm) {
      if (ts < nt)
        asm volatile("s_waitcnt vmcnt(%0)" ::"i"(LPT) : "memory");
      else
        asm volatile("s_waitcnt vmcnt(0)" ::: "memory");
    }
    __builtin_amdgcn_s_barrier();
    __builtin_amdgcn_s_setprio(1);
#pragma unroll
    for (int m = 0; m < 4; m++)
#pragma unroll
      for (int j = 0; j < NB; j++)
        acc[m][nh * NB + j] = __builtin_amdgcn_mfma_f32_16x16x32_f16(
            a[m], b[j], acc[m][nh * NB + j], 0, 0, 0);
    __builtin_amdgcn_s_setprio(0);
    MEMFENCE;
    __builtin_amdgcn_s_barrier();
    MEMFENCE;
  };

  for (int t = 0; t < nt; ++t) {
    const int t2 = t + 2;
    phase(0, 0, 0, t2, false);
    phase(0, 1, 1, t2, false);
    phase(1, 0, 2, t2, false);
    phase(1, 1, 3, t2, true);  // vmcnt(LPT): t+1 landed, t+2 in flight
    // rotate buffers (t -> t+1)
    _Float16* ta = sa0; sa0 = sa1; sa1 = sa2; sa2 = ta;
    _Float16* tb = sb0; sb0 = sb1; sb1 = sb2; sb2 = tb;
  }

  // epilogue: C/D layout col = lane&15, row = (lane>>4)*4 + reg
  const int r0 = hi * 4;
  const int c0 = frow;
#pragma unroll
  for (int n = 0; n < NW; n++) {
    const int col = bcol + wc + n * 16 + c0;
    const float bv = bias[col];
#pragma unroll
    for (int m = 0; m < 4; m++) {
#pragma unroll
      for (int r = 0; r < 4; r++) {
        const int row = brow + wr + m * 16 + r0 + r;
        float v = acc[m][n][r] + bv;
        if (EPI == 1) v = 0.5f * tanhf(v);
        if (EPI == 2)
          ((float*)Cout)[(size_t)row * N + col] = v;
        else
          ((_Float16*)Cout)[(size_t)row * N + col] = (_Float16)v;
      }
    }
  }
}

// ---------------------------------------------------------------------------
extern "C" void kernel_launch(void* const* d_in, const int* in_sizes, int n_in,
                              void* d_out, int out_size, void* d_ws,
                              size_t ws_size, hipStream_t stream) {
  (void)in_sizes;
  (void)n_in;
  (void)out_size;
  (void)ws_size;

  const float* x = (const float*)d_in[0];        // [4096,1024]
  const float* W_embed = (const float*)d_in[1];  // [2048,1024]
  const float* b_embed = (const float*)d_in[2];  // [2048]
  const float* W_layers = (const float*)d_in[3]; // [3,2048,2048]
  const float* b_layers = (const float*)d_in[4]; // [3,2048]
  const float* W_head = (const float*)d_in[5];   // [1024,2048]
  const float* b_head = (const float*)d_in[6];   // [1024]

  const int B = 4096, I = 1024, H = 2048, O = 1024;

  char* w = (char*)d_ws;
  auto carve = [&](size_t bytes) {
    char* p = w;
    w += (bytes + 255) & ~(size_t)255;
    return p;
  };
  _Float16* xh = (_Float16*)carve((size_t)B * I * 2);
  _Float16* Weh = (_Float16*)carve((size_t)H * I * 2);
  _Float16* Wlh = (_Float16*)carve((size_t)3 * H * H * 2);
  _Float16* Whh = (_Float16*)carve((size_t)O * H * 2);
  _Float16* bufE = (_Float16*)carve((size_t)B * H * 2);
  _Float16* bufA = (_Float16*)carve((size_t)B * H * 2);

  const long n0 = (long)B * I, n1 = (long)H * I, n2 = (long)3 * H * H,
             n3 = (long)O * H;
  const long nb0 = n0 / 2048, nb1 = n1 / 2048, nb2 = n2 / 2048,
             nb3 = n3 / 2048;
  cvt_all<<<(int)(nb0 + nb1 + nb2 + nb3), 256, 0, stream>>>(
      x, W_embed, W_layers, W_head, xh, Weh, Wlh, Whh, nb0, nb1, nb2);

  dim3 blk(512);
  // all grids: 16x16 tiles = 256 blocks = 1 block/CU
  // x_emb = x @ W_embed^T + b_embed            [B,H], f16
  gemm4p<0, 4><<<256, blk, 0, stream>>>(xh, Weh, b_embed, bufE, H, I);
  // h0 = 0.5*tanh(x_emb @ W0^T + b0)           [B,H], f16
  gemm4p<1, 4><<<256, blk, 0, stream>>>(bufE, Wlh, b_layers, bufA, H, H);
  // h1 = 0.5*tanh(h0 @ W1^T + b1)              [B,H], f16
  gemm4p<1, 4><<<256, blk, 0, stream>>>(bufA, Wlh + (size_t)H * H,
                                        b_layers + H, bufE, H, H);
  // h2 = 0.5*tanh(h1 @ W2^T + b2)              [B,H], f16
  gemm4p<1, 4><<<256, blk, 0, stream>>>(bufE, Wlh + (size_t)2 * H * H,
                                        b_layers + 2 * H, bufA, H, H);
  // out = h2 @ W_head^T + b_head               [B,O], f32  (BN=64)
  gemm4p<2, 2><<<256, blk, 0, stream>>>(bufA, Whh, b_head, d_out, O, H);
}

// Round 11
// 204.638 us; speedup vs baseline: 1.0893x; 1.0047x over previous
//
#include <hip/hip_runtime.h>
#include <cmath>

typedef _Float16 half8 __attribute__((ext_vector_type(8)));
typedef float f32x4 __attribute__((ext_vector_type(4)));

// ---------------- merged f32 -> f16 conversion (one dispatch) ---------------
__global__ void cvt_all(const float* __restrict__ s0, const float* __restrict__ s1,
                        const float* __restrict__ s2, const float* __restrict__ s3,
                        _Float16* __restrict__ d0, _Float16* __restrict__ d1,
                        _Float16* __restrict__ d2, _Float16* __restrict__ d3,
                        long nb0, long nb1, long nb2) {
  long b = blockIdx.x;
  const float* s;
  _Float16* d;
  if (b < nb0) {
    s = s0; d = d0;
  } else if (b < nb0 + nb1) {
    s = s1; d = d1; b -= nb0;
  } else if (b < nb0 + nb1 + nb2) {
    s = s2; d = d2; b -= nb0 + nb1;
  } else {
    s = s3; d = d3; b -= nb0 + nb1 + nb2;
  }
  long i = b * 2048 + (long)threadIdx.x * 8;
  const float4* p = (const float4*)(s + i);
  float4 a = p[0];
  float4 c = p[1];
  half8 h = {(_Float16)a.x, (_Float16)a.y, (_Float16)a.z, (_Float16)a.w,
             (_Float16)c.x, (_Float16)c.y, (_Float16)c.z, (_Float16)c.w};
  *(half8*)(d + i) = h;
}

// ---------------- GEMM: C[m,n] = sum_k A[m,k]*B[n,k]  (both K-major) --------
// EPI: 0 = acc+bias -> f16 ; 1 = 0.5*tanh(acc+bias) -> f16 ; 2 = acc+bias -> f32
// NW:  B-fragments per wave. BN = NW*32 (4 -> BN=128, 2 -> BN=64).
// BM=256, BK=64, 512 threads = 8 waves (4M x 2N), wave tile 64 x (BN/2).
// T14 REGISTER staging (global->reg->ds_write), double-buffered LDS (96 KB),
// ONE barrier per K-tile, zero exposed drains:
//   iter t: ds_read frags(buf[p]) ; ds_write tile t+1 regs -> buf[p^1]
//           (buf[p^1] dead since prev barrier; writes ride the LDS pipe
//            under the MFMA window; compiler emits the counted vmcnt before
//            the first ds_write) ; gload(t+2)->regs (full-iter latency
//           cover) ; setprio(1) 32 MFMA setprio(0) ; lgkmcnt(0) ; s_barrier.
// RAW: buf[p] was written last iter; its writes drained at last iter's
// lgkmcnt(0)+barrier. WAR: all waves' reads of buf[p^1] finished last iter
// (lgkmcnt(0) covers reads too).
// T2 swizzle now applied directly on the ds_write address (reg-staging has
// no linear-dest constraint): elem (row, c8) -> row*64 + ((c8 ^ (row&7))*8);
// ds_read uses the same XOR (xr = frow&7).
// Grid: 256 blocks = 16x16 tiles; 2-D XCD rects (4 rows x 8 cols of tiles).
template <int EPI, int NW>
__global__ __launch_bounds__(512, 2) void gemmrs(
    const _Float16* __restrict__ A, const _Float16* __restrict__ Bm,
    const float* __restrict__ bias, void* __restrict__ Cout, int N, int K) {
  constexpr int BN = NW * 32;
  constexpr int BLOADS = BN / 64;  // B row-groups (2 or 1)
  __shared__ _Float16 As[2][256 * 64];
  __shared__ _Float16 Bs[2][BN * 64];

  const int tid = threadIdx.x;
  const int lane = tid & 63;
  const int wave = tid >> 6;

  // 2-D XCD rects on the 16x16 tile grid (256 blocks): each XCD owns 4x8.
  const int bid = blockIdx.x;
  const int xcd = bid & 7;
  const int idx = bid >> 3;  // 0..31
  const int brow = ((xcd >> 1) * 4 + (idx & 3)) * 256;
  const int bcol = ((xcd & 1) * 8 + (idx >> 2)) * BN;

  const int wr = (wave >> 1) * 64;        // 4 M-waves, 64 rows each
  const int wc = (wave & 1) * (BN / 2);   // 2 N-waves

  // staging geometry: thread covers row sr (+64i), 16B chunk scc.
  const int sr = tid >> 3;   // 0..63
  const int scc = tid & 7;   // chunk index
  const _Float16* Ag = A + (size_t)(brow + sr) * K + scc * 8;
  const _Float16* Bg = Bm + (size_t)(bcol + sr) * K + scc * 8;

  // swizzled LDS write offsets (element units); row&7 == sr&7 for all i.
  int wOff[4];
#pragma unroll
  for (int i = 0; i < 4; i++)
    wOff[i] = (sr + 64 * i) * 64 + ((scc ^ (sr & 7)) * 8);

  // MFMA fragment geometry (16x16x32): row=lane&15, k-half=(lane>>4)*8
  const int frow = lane & 15;
  const int hi = lane >> 4;
  const int xr = lane & 7;  // read-side XOR (matches write swizzle)

  int aoff[4], boff[NW];
#pragma unroll
  for (int m = 0; m < 4; m++) aoff[m] = (wr + m * 16 + frow) * 64;
#pragma unroll
  for (int n = 0; n < NW; n++) boff[n] = (wc + n * 16 + frow) * 64;
  const int ch0 = (hi ^ xr) * 8;
  const int ch1 = ((4 + hi) ^ xr) * 8;

  f32x4 acc[4][NW];
#pragma unroll
  for (int m = 0; m < 4; m++)
#pragma unroll
    for (int n = 0; n < NW; n++) acc[m][n] = f32x4{0.f, 0.f, 0.f, 0.f};

  half8 aR[4], bR[BLOADS];
  auto gload = [&](int t) {
#pragma unroll
    for (int i = 0; i < 4; i++)
      aR[i] = *(const half8*)(Ag + t * 64 + (size_t)i * 64 * K);
#pragma unroll
    for (int i = 0; i < BLOADS; i++)
      bR[i] = *(const half8*)(Bg + t * 64 + (size_t)i * 64 * K);
  };
  auto swrite = [&](_Float16* sa, _Float16* sb) {
#pragma unroll
    for (int i = 0; i < 4; i++) *(half8*)(sa + wOff[i]) = aR[i];
#pragma unroll
    for (int i = 0; i < BLOADS; i++) *(half8*)(sb + wOff[i]) = bR[i];
  };

  const int nt = K >> 6;  // 16 or 32 here

  // prologue: tile 0 -> LDS buf0; tile 1 -> regs; publish buf0
  gload(0);
  swrite(As[0], Bs[0]);  // compiler inserts the vmcnt before these writes
  gload(1);
  asm volatile("s_waitcnt lgkmcnt(0)" ::: "memory");
  __builtin_amdgcn_s_barrier();

  int p = 0;
  for (int t = 0; t < nt; ++t) {
    const _Float16* sa = As[p];
    const _Float16* sb = Bs[p];

    // reads of tile t (issue first so MFMA can start as soon as they land)
    half8 a0[4], a1[4], b0[NW], b1[NW];
#pragma unroll
    for (int m = 0; m < 4; m++) a0[m] = *(const half8*)(sa + aoff[m] + ch0);
#pragma unroll
    for (int n = 0; n < NW; n++) b0[n] = *(const half8*)(sb + boff[n] + ch0);
#pragma unroll
    for (int m = 0; m < 4; m++) a1[m] = *(const half8*)(sa + aoff[m] + ch1);
#pragma unroll
    for (int n = 0; n < NW; n++) b1[n] = *(const half8*)(sb + boff[n] + ch1);

    // tile t+1: regs -> buf[p^1] (dead buffer; writes complete under MFMA)
    if (t + 1 < nt) swrite(As[p ^ 1], Bs[p ^ 1]);
    // tile t+2: issue global loads (full-iteration latency cover)
    if (t + 2 < nt) gload(t + 2);

    __builtin_amdgcn_s_setprio(1);
#pragma unroll
    for (int m = 0; m < 4; m++)
#pragma unroll
      for (int n = 0; n < NW; n++)
        acc[m][n] =
            __builtin_amdgcn_mfma_f32_16x16x32_f16(a0[m], b0[n], acc[m][n], 0, 0, 0);
#pragma unroll
    for (int m = 0; m < 4; m++)
#pragma unroll
      for (int n = 0; n < NW; n++)
        acc[m][n] =
            __builtin_amdgcn_mfma_f32_16x16x32_f16(a1[m], b1[n], acc[m][n], 0, 0, 0);
    __builtin_amdgcn_s_setprio(0);

    // all my DS ops (reads of buf[p] + writes to buf[p^1]) drained, then sync
    asm volatile("s_waitcnt lgkmcnt(0)" ::: "memory");
    __builtin_amdgcn_s_barrier();
    p ^= 1;
  }

  // epilogue: C/D layout col = lane&15, row = (lane>>4)*4 + reg
  const int r0 = hi * 4;
  const int c0 = frow;
#pragma unroll
  for (int n = 0; n < NW; n++) {
    const int col = bcol + wc + n * 16 + c0;
    const float bv = bias[col];
#pragma unroll
    for (int m = 0; m < 4; m++) {
#pragma unroll
      for (int r = 0; r < 4; r++) {
        const int row = brow + wr + m * 16 + r0 + r;
        float v = acc[m][n][r] + bv;
        if (EPI == 1) v = 0.5f * tanhf(v);
        if (EPI == 2)
          ((float*)Cout)[(size_t)row * N + col] = v;
        else
          ((_Float16*)Cout)[(size_t)row * N + col] = (_Float16)v;
      }
    }
  }
}

// ---------------------------------------------------------------------------
extern "C" void kernel_launch(void* const* d_in, const int* in_sizes, int n_in,
                              void* d_out, int out_size, void* d_ws,
                              size_t ws_size, hipStream_t stream) {
  (void)in_sizes;
  (void)n_in;
  (void)out_size;
  (void)ws_size;

  const float* x = (const float*)d_in[0];        // [4096,1024]
  const float* W_embed = (const float*)d_in[1];  // [2048,1024]
  const float* b_embed = (const float*)d_in[2];  // [2048]
  const float* W_layers = (const float*)d_in[3]; // [3,2048,2048]
  const float* b_layers = (const float*)d_in[4]; // [3,2048]
  const float* W_head = (const float*)d_in[5];   // [1024,2048]
  const float* b_head = (const float*)d_in[6];   // [1024]

  const int B = 4096, I = 1024, H = 2048, O = 1024;

  char* w = (char*)d_ws;
  auto carve = [&](size_t bytes) {
    char* p = w;
    w += (bytes + 255) & ~(size_t)255;
    return p;
  };
  _Float16* xh = (_Float16*)carve((size_t)B * I * 2);
  _Float16* Weh = (_Float16*)carve((size_t)H * I * 2);
  _Float16* Wlh = (_Float16*)carve((size_t)3 * H * H * 2);
  _Float16* Whh = (_Float16*)carve((size_t)O * H * 2);
  _Float16* bufE = (_Float16*)carve((size_t)B * H * 2);
  _Float16* bufA = (_Float16*)carve((size_t)B * H * 2);

  const long n0 = (long)B * I, n1 = (long)H * I, n2 = (long)3 * H * H,
             n3 = (long)O * H;
  const long nb0 = n0 / 2048, nb1 = n1 / 2048, nb2 = n2 / 2048,
             nb3 = n3 / 2048;
  cvt_all<<<(int)(nb0 + nb1 + nb2 + nb3), 256, 0, stream>>>(
      x, W_embed, W_layers, W_head, xh, Weh, Wlh, Whh, nb0, nb1, nb2);

  dim3 blk(512);
  // all grids: 16x16 tiles = 256 blocks = 1 block/CU
  // x_emb = x @ W_embed^T + b_embed            [B,H], f16
  gemmrs<0, 4><<<256, blk, 0, stream>>>(xh, Weh, b_embed, bufE, H, I);
  // h0 = 0.5*tanh(x_emb @ W0^T + b0)           [B,H], f16
  gemmrs<1, 4><<<256, blk, 0, stream>>>(bufE, Wlh, b_layers, bufA, H, H);
  // h1 = 0.5*tanh(h0 @ W1^T + b1)              [B,H], f16
  gemmrs<1, 4><<<256, blk, 0, stream>>>(bufA, Wlh + (size_t)H * H,
                                        b_layers + H, bufE, H, H);
  // h2 = 0.5*tanh(h1 @ W2^T + b2)              [B,H], f16
  gemmrs<1, 4><<<256, blk, 0, stream>>>(bufE, Wlh + (size_t)2 * H * H,
                                        b_layers + 2 * H, bufA, H, H);
  // out = h2 @ W_head^T + b_head               [B,O], f32  (BN=64)
  gemmrs<2, 2><<<256, blk, 0, stream>>>(bufA, Whh, b_head, d_out, O, H);
}